// Round 1
// baseline (194.319 us; speedup 1.0000x reference)
//
#include <hip/hip_runtime.h>

#define DEV __device__ __forceinline__

typedef unsigned short u16;
typedef __bf16 bf16x8 __attribute__((ext_vector_type(8)));
typedef float fx4 __attribute__((ext_vector_type(4)));

#define NPIX 65536
#define OFF_WCAT  16777216
#define OFF_WOUT  16908288
#define OFF_Q     16941056
#define OFF_BIAS  67272704
#define OFF_GATE  68321280
#define TEN_ELEMS 8388608  // u16 elements per Q/K/V tensor

DEV u16 f2bf(float f){
  unsigned u = __builtin_bit_cast(unsigned, f);
  u += 0x7fffu + ((u>>16)&1u);
  return (u16)(u>>16);
}
DEV float bf2f(u16 s){ return __builtin_bit_cast(float, ((unsigned)s)<<16); }

typedef __attribute__((address_space(1))) unsigned gas_t;
typedef __attribute__((address_space(3))) unsigned las_t;
DEV void gl16(const void* g, void* l){
  __builtin_amdgcn_global_load_lds((gas_t*)g, (las_t*)l, 16, 0, 0);
}

// XOR-ish swizzle for [row][32] bf16 LDS tiles (row stride 64B): chunk' = (cc + row/2) & 3
DEV int swz(int row, int cc){ return row*32 + (((cc + (row>>1))&3)<<3); }

// ---------------- K0: weight convert/transpose ----------------
__global__ __launch_bounds__(256) void k_prep(const float* __restrict__ Wqkv,
                                              const float* __restrict__ Wgate,
                                              const float* __restrict__ Wout,
                                              u16* __restrict__ wcat, u16* __restrict__ woutT){
  int idx = blockIdx.x*256 + threadIdx.x;   // grid = 256 blocks -> idx < 65536
  int n = idx>>7, k = idx&127;
  float v = (n<384) ? Wqkv[k*384 + n] : Wgate[k*128 + (n-384)];
  wcat[idx] = f2bf(v);
  if (idx < 16384){
    woutT[idx] = f2bf(Wout[k*128 + n]);
  }
}

// ---------------- K1: LN + bias projection ----------------
__global__ __launch_bounds__(256) void k_ln(const float* __restrict__ x,
                                            const float* __restrict__ lng,
                                            const float* __restrict__ lnb,
                                            const float* __restrict__ Wb,
                                            u16* __restrict__ lnx, float* __restrict__ bias_s){
  int lane = threadIdx.x & 63;
  int wid  = (blockIdx.x*256 + threadIdx.x)>>6;
  int nw   = (gridDim.x*256)>>6;
  int c0 = lane<<1;
  float g0 = lng[c0], g1 = lng[c0+1], be0 = lnb[c0], be1 = lnb[c0+1];
  float4 wb0 = *(const float4*)(Wb + (c0<<2));
  float4 wb1 = *(const float4*)(Wb + (c0<<2) + 4);
  for (int p = wid; p < NPIX; p += nw){
    float2 xv = *(const float2*)(x + (((size_t)p)<<7) + c0);
    float s = xv.x + xv.y;
    float s2 = xv.x*xv.x + xv.y*xv.y;
    #pragma unroll
    for (int msk=32; msk>=1; msk>>=1){ s += __shfl_xor(s,msk); s2 += __shfl_xor(s2,msk); }
    float mu = s*(1.f/128.f);
    float var = s2*(1.f/128.f) - mu*mu;
    float rs = rsqrtf(var + 1e-5f);
    float y0 = (xv.x-mu)*rs*g0 + be0;
    float y1 = (xv.y-mu)*rs*g1 + be1;
    unsigned pk = (unsigned)f2bf(y0) | (((unsigned)f2bf(y1))<<16);
    *(unsigned*)(lnx + (((size_t)p)<<7) + c0) = pk;
    float d0 = y0*wb0.x + y1*wb1.x;
    float d1 = y0*wb0.y + y1*wb1.y;
    float d2 = y0*wb0.z + y1*wb1.z;
    float d3 = y0*wb0.w + y1*wb1.w;
    #pragma unroll
    for (int msk=32; msk>=1; msk>>=1){
      d0 += __shfl_xor(d0,msk); d1 += __shfl_xor(d1,msk);
      d2 += __shfl_xor(d2,msk); d3 += __shfl_xor(d3,msk);
    }
    if (lane==0){
      int pi = p>>8, pj = p&255;
      int o = (pj<<8) + pi;          // bias_s[h][j=pj][k=pi]
      bias_s[o] = d0;
      bias_s[65536 + o] = d1;
      bias_s[131072 + o] = d2;
      bias_s[196608 + o] = d3;
    }
  }
}

// ---------------- K2: qkv+gate projection GEMM ----------------
__global__ __launch_bounds__(256,3) void k_qkv(const u16* __restrict__ lnx,
                                               const u16* __restrict__ wcat,
                                               const float* __restrict__ b_gate,
                                               u16* __restrict__ qkv, u16* __restrict__ gateb){
  __shared__ __align__(16) u16 As[4096];
  __shared__ __align__(16) u16 Bs[4096];
  int t = threadIdx.x, l = t&63, w = t>>6;
  int m0 = blockIdx.x<<7, n0 = blockIdx.y<<7;
  int wm = w>>1, wn = w&1;
  int rbase = (l>>4)<<2, cbase = l&15;
  fx4 acc[4][4] = {};
  for (int ks=0; ks<4; ++ks){
    int k0 = ks<<5;
    __syncthreads();
    #pragma unroll
    for (int s=0; s<2; ++s){
      int idx = (s<<8) + t;
      int row = idx>>2, ccL = idx&3;
      int ccG = (ccL - (row>>1)) & 3;
      gl16(lnx  + (size_t)(m0+row)*128 + k0 + (ccG<<3), As + (((s<<2)+w)<<9));
      gl16(wcat + (size_t)(n0+row)*128 + k0 + (ccG<<3), Bs + (((s<<2)+w)<<9));
    }
    asm volatile("s_waitcnt vmcnt(0)" ::: "memory");
    __syncthreads();
    bf16x8 a[4], b[4];
    #pragma unroll
    for (int mi=0; mi<4; ++mi)
      a[mi] = *(const bf16x8*)(As + swz((wm<<6)+(mi<<4)+cbase, l>>4));
    #pragma unroll
    for (int ni=0; ni<4; ++ni)
      b[ni] = *(const bf16x8*)(Bs + swz((wn<<6)+(ni<<4)+cbase, l>>4));
    #pragma unroll
    for (int mi=0; mi<4; ++mi)
      #pragma unroll
      for (int ni=0; ni<4; ++ni)
        acc[mi][ni] = __builtin_amdgcn_mfma_f32_16x16x32_bf16(a[mi], b[ni], acc[mi][ni], 0,0,0);
  }
  if (n0 < 384){
    #pragma unroll
    for (int mi=0; mi<4; ++mi)
      #pragma unroll
      for (int ni=0; ni<4; ++ni){
        int n = n0 + (wn<<6) + (ni<<4) + cbase;
        int c = n/12; int tt = n - c*12;
        #pragma unroll
        for (int r=0; r<4; ++r){
          int m = m0 + (wm<<6) + (mi<<4) + rbase + r;
          size_t dst = (size_t)(tt>>2)*TEN_ELEMS
                     + ((size_t)(((m>>8)<<2) + (tt&3))*256 + (m&255))*32 + c;
          qkv[dst] = f2bf(acc[mi][ni][r]);
        }
      }
  } else {
    #pragma unroll
    for (int mi=0; mi<4; ++mi)
      #pragma unroll
      for (int ni=0; ni<4; ++ni){
        int gi = (wn<<6) + (ni<<4) + cbase;
        float bg = b_gate[gi];
        #pragma unroll
        for (int r=0; r<4; ++r){
          int m = m0 + (wm<<6) + (mi<<4) + rbase + r;
          float v = acc[mi][ni][r] + bg;
          float sg = 1.f/(1.f + __expf(-v));
          gateb[(((size_t)m)<<7) + gi] = f2bf(sg);
        }
      }
  }
}

// ---------------- K3: attention ----------------
__global__ __launch_bounds__(256,2) void k_attn(const u16* __restrict__ Qb,
                                                const u16* __restrict__ Kb,
                                                const u16* __restrict__ Vb,
                                                const float* __restrict__ bias_s,
                                                const u16* __restrict__ gateb,
                                                u16* __restrict__ Og){
  __shared__ __align__(16) u16 Ks[8192];
  __shared__ __align__(16) u16 Vs[8192];
  __shared__ __align__(16) u16 Pls[4][2176];   // per-wave [16][136]
  int t = threadIdx.x, l = t&63, w = t>>6;
  int i = blockIdx.x>>2, h = blockIdx.x&3;
  size_t base2 = ((size_t)(i*4+h))<<13;        // *8192 elements
  #pragma unroll
  for (int s=0; s<4; ++s){
    int idx = (s<<8) + t;
    gl16(Kb + base2 + ((size_t)idx<<3), Ks + (((s<<2)+w)<<9));
    gl16(Vb + base2 + ((size_t)idx<<3), Vs + (((s<<2)+w)<<9));
  }
  asm volatile("s_waitcnt vmcnt(0)" ::: "memory");
  __syncthreads();
  int cbase = l&15, rbase = (l>>4)<<2;
  bf16x8 kf[16];
  #pragma unroll
  for (int f=0; f<16; ++f)
    kf[f] = *(const bf16x8*)(Ks + ((f<<4)+cbase)*32 + ((l>>4)<<3));
  bf16x8 vf[8][2];
  #pragma unroll
  for (int ks=0; ks<8; ++ks)
    #pragma unroll
    for (int cf=0; cf<2; ++cf){
      bf16x8 v;
      #pragma unroll
      for (int e=0; e<8; ++e)
        v[e] = __builtin_bit_cast(__bf16, Vs[((ks<<5) + ((l>>4)<<3) + e)*32 + (cf<<4) + cbase]);
      vf[ks][cf] = v;
    }
  u16* myP = &Pls[w][0];
  const float SCALE = 0.17677669529663687f;   // 1/sqrt(32)
  #pragma unroll 1
  for (int sj=0; sj<4; ++sj){
    int jloc = (w<<6) + (sj<<4);
    bf16x8 qf = *(const bf16x8*)(Qb + base2 + (size_t)(jloc + cbase)*32 + ((l>>4)<<3));
    fx4 sacc[16];
    #pragma unroll
    for (int f=0; f<16; ++f) sacc[f] = (fx4){0.f,0.f,0.f,0.f};
    #pragma unroll
    for (int f=0; f<16; ++f)
      sacc[f] = __builtin_amdgcn_mfma_f32_16x16x32_bf16(qf, kf[f], sacc[f], 0,0,0);
    const float* bp = bias_s + ((size_t)((h<<8) + jloc + rbase)<<8) + cbase;
    #pragma unroll
    for (int f=0; f<16; ++f)
      #pragma unroll
      for (int r=0; r<4; ++r)
        sacc[f][r] = sacc[f][r]*SCALE + bp[(r<<8) + (f<<4)];
    float mx[4], inv[4];
    #pragma unroll
    for (int r=0; r<4; ++r){
      float m = sacc[0][r];
      #pragma unroll
      for (int f=1; f<16; ++f) m = fmaxf(m, sacc[f][r]);
      m = fmaxf(m, __shfl_xor(m,1));
      m = fmaxf(m, __shfl_xor(m,2));
      m = fmaxf(m, __shfl_xor(m,4));
      m = fmaxf(m, __shfl_xor(m,8));
      mx[r] = m;
    }
    #pragma unroll
    for (int r=0; r<4; ++r){
      float sum = 0.f;
      #pragma unroll
      for (int f=0; f<16; ++f){ float p = __expf(sacc[f][r]-mx[r]); sacc[f][r] = p; sum += p; }
      sum += __shfl_xor(sum,1); sum += __shfl_xor(sum,2);
      sum += __shfl_xor(sum,4); sum += __shfl_xor(sum,8);
      inv[r] = 1.f/sum;
    }
    fx4 oacc[2] = {};
    #pragma unroll
    for (int half=0; half<2; ++half){
      #pragma unroll
      for (int f=0; f<8; ++f){
        int fk = (half<<3)+f;
        #pragma unroll
        for (int r=0; r<4; ++r)
          myP[(rbase+r)*136 + (f<<4) + cbase] = f2bf(sacc[fk][r]*inv[r]);
      }
      asm volatile("s_waitcnt lgkmcnt(0)" ::: "memory");
      #pragma unroll
      for (int k2=0; k2<4; ++k2){
        const bf16x8 pa = *(const bf16x8*)(myP + cbase*136 + (k2<<5) + ((l>>4)<<3));
        int ks = (half<<2)+k2;
        oacc[0] = __builtin_amdgcn_mfma_f32_16x16x32_bf16(pa, vf[ks][0], oacc[0], 0,0,0);
        oacc[1] = __builtin_amdgcn_mfma_f32_16x16x32_bf16(pa, vf[ks][1], oacc[1], 0,0,0);
      }
    }
    #pragma unroll
    for (int cf=0; cf<2; ++cf)
      #pragma unroll
      for (int r=0; r<4; ++r){
        int j = jloc + rbase + r;
        size_t pix = (((size_t)i)<<8) + j;
        int ch = (((cf<<4) + cbase)<<2) + h;
        float gg = bf2f(gateb[(pix<<7) + ch]);
        Og[(pix<<7) + ch] = f2bf(oacc[cf][r]*gg);
      }
  }
}

// ---------------- K4: output GEMM ----------------
__global__ __launch_bounds__(256,3) void k_out(const u16* __restrict__ og,
                                               const u16* __restrict__ wT,
                                               const float* __restrict__ bo,
                                               float* __restrict__ out){
  __shared__ __align__(16) u16 As[4096];
  __shared__ __align__(16) u16 Bs[4096];
  int t = threadIdx.x, l = t&63, w = t>>6;
  int m0 = blockIdx.x<<7;
  int wm = w>>1, wn = w&1;
  int rbase = (l>>4)<<2, cbase = l&15;
  fx4 acc[4][4] = {};
  for (int ks=0; ks<4; ++ks){
    int k0 = ks<<5;
    __syncthreads();
    #pragma unroll
    for (int s=0; s<2; ++s){
      int idx = (s<<8)+t, row = idx>>2, ccL = idx&3;
      int ccG = (ccL - (row>>1))&3;
      gl16(og + (size_t)(m0+row)*128 + k0 + (ccG<<3), As + (((s<<2)+w)<<9));
      gl16(wT + (size_t)row*128 + k0 + (ccG<<3), Bs + (((s<<2)+w)<<9));
    }
    asm volatile("s_waitcnt vmcnt(0)" ::: "memory");
    __syncthreads();
    bf16x8 a[4], b[4];
    #pragma unroll
    for (int mi=0; mi<4; ++mi)
      a[mi] = *(const bf16x8*)(As + swz((wm<<6)+(mi<<4)+cbase, l>>4));
    #pragma unroll
    for (int ni=0; ni<4; ++ni)
      b[ni] = *(const bf16x8*)(Bs + swz((wn<<6)+(ni<<4)+cbase, l>>4));
    #pragma unroll
    for (int mi=0; mi<4; ++mi)
      #pragma unroll
      for (int ni=0; ni<4; ++ni)
        acc[mi][ni] = __builtin_amdgcn_mfma_f32_16x16x32_bf16(a[mi], b[ni], acc[mi][ni], 0,0,0);
  }
  #pragma unroll
  for (int mi=0; mi<4; ++mi)
    #pragma unroll
    for (int ni=0; ni<4; ++ni){
      int n = (wn<<6)+(ni<<4)+cbase;
      float bn = bo[n];
      #pragma unroll
      for (int r=0; r<4; ++r){
        int m = m0 + (wm<<6)+(mi<<4)+rbase+r;
        out[(((size_t)m)<<7)+n] = acc[mi][ni][r] + bn;
      }
    }
}

extern "C" void kernel_launch(void* const* d_in, const int* in_sizes, int n_in,
                              void* d_out, int out_size, void* d_ws, size_t ws_size,
                              hipStream_t stream) {
  (void)in_sizes; (void)n_in; (void)out_size; (void)ws_size;
  const float* x2d    = (const float*)d_in[0];
  const float* ln_g   = (const float*)d_in[1];
  const float* ln_b   = (const float*)d_in[2];
  const float* W_qkv  = (const float*)d_in[3];
  const float* W_bias = (const float*)d_in[4];
  const float* W_gate = (const float*)d_in[5];
  const float* b_gate = (const float*)d_in[6];
  const float* W_out  = (const float*)d_in[7];
  const float* b_out  = (const float*)d_in[8];
  float* out = (float*)d_out;
  char* ws = (char*)d_ws;
  u16*   lnx    = (u16*)(ws);
  u16*   wcat   = (u16*)(ws + OFF_WCAT);
  u16*   woutT  = (u16*)(ws + OFF_WOUT);
  u16*   qkvb   = (u16*)(ws + OFF_Q);
  float* bias_s = (float*)(ws + OFF_BIAS);
  u16*   gateb  = (u16*)(ws + OFF_GATE);
  u16*   og     = lnx;   // reuse: lnx dead after k_qkv

  hipLaunchKernelGGL(k_prep, dim3(256),      dim3(256), 0, stream, W_qkv, W_gate, W_out, wcat, woutT);
  hipLaunchKernelGGL(k_ln,   dim3(2048),     dim3(256), 0, stream, x2d, ln_g, ln_b, W_bias, lnx, bias_s);
  hipLaunchKernelGGL(k_qkv,  dim3(512,4),    dim3(256), 0, stream, lnx, wcat, b_gate, qkvb, gateb);
  hipLaunchKernelGGL(k_attn, dim3(1024),     dim3(256), 0, stream, qkvb, qkvb+TEN_ELEMS, qkvb+2*TEN_ELEMS, bias_s, gateb, og);
  hipLaunchKernelGGL(k_out,  dim3(512),      dim3(256), 0, stream, og, woutT, b_out, out);
}

// Round 2
// 128.848 us; speedup vs baseline: 1.5081x; 1.5081x over previous
//
#include <hip/hip_runtime.h>

#define DEV __device__ __forceinline__

typedef unsigned short u16;
typedef __bf16 bf16x8 __attribute__((ext_vector_type(8)));
typedef u16 u16x4 __attribute__((ext_vector_type(4)));
typedef float fx4 __attribute__((ext_vector_type(4)));

#define NPIX 65536
#define OFF_WCAT  16777216
#define OFF_WOUT  16908288
#define OFF_Q     16941056
#define OFF_BIAS  67272704
#define OFF_GATE  68321280
#define TEN_ELEMS 8388608  // u16 elements per Q/K/V tensor

DEV u16 f2bf(float f){
  unsigned u = __builtin_bit_cast(unsigned, f);
  u += 0x7fffu + ((u>>16)&1u);
  return (u16)(u>>16);
}
DEV float bf2f(u16 s){ return __builtin_bit_cast(float, ((unsigned)s)<<16); }

typedef __attribute__((address_space(1))) unsigned gas_t;
typedef __attribute__((address_space(3))) unsigned las_t;
DEV void gl16(const void* g, void* l){
  __builtin_amdgcn_global_load_lds((gas_t*)g, (las_t*)l, 16, 0, 0);
}

// XOR-ish swizzle for [row][32] bf16 LDS tiles (row stride 64B): chunk' = (cc + row/2) & 3
DEV int swz(int row, int cc){ return row*32 + (((cc + (row>>1))&3)<<3); }

// ---------------- K0: weight convert/transpose (column-permuted) ----------------
// wcat column n' in [0,512): tt = n'>>7 (0=q,1=k,2=v,3=gate), h=(n'>>5)&3, c=n'&31
//   qkv orig col = c*12 + tt*4 + h ; gate orig col = c*4 + h
// woutT[n][k'] with k' = h*32+c  <->  orig k = c*4+h
__global__ __launch_bounds__(256) void k_prep(const float* __restrict__ Wqkv,
                                              const float* __restrict__ Wgate,
                                              const float* __restrict__ Wout,
                                              u16* __restrict__ wcat, u16* __restrict__ woutT){
  int idx = blockIdx.x*256 + threadIdx.x;   // grid = 256 blocks -> idx < 65536
  int np = idx>>7, k = idx&127;
  int tt = np>>7, hh = (np>>5)&3, c = np&31;
  float v;
  if (tt < 3) v = Wqkv[k*384 + c*12 + tt*4 + hh];
  else        v = Wgate[k*128 + c*4 + hh];
  wcat[idx] = f2bf(v);
  if (idx < 16384){
    int n = idx>>7, kp = idx&127;
    int h2 = kp>>5, c2 = kp&31;
    woutT[idx] = f2bf(Wout[(c2*4 + h2)*128 + n]);
  }
}

// ---------------- K1: LN + bias projection ----------------
__global__ __launch_bounds__(256) void k_ln(const float* __restrict__ x,
                                            const float* __restrict__ lng,
                                            const float* __restrict__ lnb,
                                            const float* __restrict__ Wb,
                                            u16* __restrict__ lnx, float* __restrict__ bias_s){
  int lane = threadIdx.x & 63;
  int wid  = (blockIdx.x*256 + threadIdx.x)>>6;
  int nw   = (gridDim.x*256)>>6;
  int c0 = lane<<1;
  float g0 = lng[c0], g1 = lng[c0+1], be0 = lnb[c0], be1 = lnb[c0+1];
  float4 wb0 = *(const float4*)(Wb + (c0<<2));
  float4 wb1 = *(const float4*)(Wb + (c0<<2) + 4);
  for (int p = wid; p < NPIX; p += nw){
    float2 xv = *(const float2*)(x + (((size_t)p)<<7) + c0);
    float s = xv.x + xv.y;
    float s2 = xv.x*xv.x + xv.y*xv.y;
    #pragma unroll
    for (int msk=32; msk>=1; msk>>=1){ s += __shfl_xor(s,msk); s2 += __shfl_xor(s2,msk); }
    float mu = s*(1.f/128.f);
    float var = s2*(1.f/128.f) - mu*mu;
    float rs = rsqrtf(var + 1e-5f);
    float y0 = (xv.x-mu)*rs*g0 + be0;
    float y1 = (xv.y-mu)*rs*g1 + be1;
    unsigned pk = (unsigned)f2bf(y0) | (((unsigned)f2bf(y1))<<16);
    *(unsigned*)(lnx + (((size_t)p)<<7) + c0) = pk;
    float d0 = y0*wb0.x + y1*wb1.x;
    float d1 = y0*wb0.y + y1*wb1.y;
    float d2 = y0*wb0.z + y1*wb1.z;
    float d3 = y0*wb0.w + y1*wb1.w;
    #pragma unroll
    for (int msk=32; msk>=1; msk>>=1){
      d0 += __shfl_xor(d0,msk); d1 += __shfl_xor(d1,msk);
      d2 += __shfl_xor(d2,msk); d3 += __shfl_xor(d3,msk);
    }
    if (lane==0){
      int pi = p>>8, pj = p&255;
      int o = (pj<<8) + pi;          // bias_s[h][j=pj][k=pi]
      bias_s[o] = d0;
      bias_s[65536 + o] = d1;
      bias_s[131072 + o] = d2;
      bias_s[196608 + o] = d3;
    }
  }
}

// ---------------- K2: qkv+gate projection GEMM ----------------
__global__ __launch_bounds__(256,3) void k_qkv(const u16* __restrict__ lnx,
                                               const u16* __restrict__ wcat,
                                               const float* __restrict__ b_gate,
                                               u16* __restrict__ qkv, u16* __restrict__ gateb){
  __shared__ __align__(16) u16 As[4096];
  __shared__ __align__(16) u16 Bs[4096];
  __shared__ __align__(16) u16 Ep[64*132];
  int t = threadIdx.x, l = t&63, w = t>>6;
  int m0 = blockIdx.x<<7, n0 = blockIdx.y<<7;
  int tt2 = n0>>7;
  int wm = w>>1, wn = w&1;
  int rbase = (l>>4)<<2, cbase = l&15;
  fx4 acc[4][4] = {};
  for (int ks=0; ks<4; ++ks){
    int k0 = ks<<5;
    __syncthreads();
    #pragma unroll
    for (int s=0; s<2; ++s){
      int idx = (s<<8) + t;
      int row = idx>>2, ccL = idx&3;
      int ccG = (ccL - (row>>1)) & 3;
      gl16(lnx  + (size_t)(m0+row)*128 + k0 + (ccG<<3), As + (((s<<2)+w)<<9));
      gl16(wcat + (size_t)(n0+row)*128 + k0 + (ccG<<3), Bs + (((s<<2)+w)<<9));
    }
    asm volatile("s_waitcnt vmcnt(0)" ::: "memory");
    __syncthreads();
    bf16x8 a[4], b[4];
    #pragma unroll
    for (int mi=0; mi<4; ++mi)
      a[mi] = *(const bf16x8*)(As + swz((wm<<6)+(mi<<4)+cbase, l>>4));
    #pragma unroll
    for (int ni=0; ni<4; ++ni)
      b[ni] = *(const bf16x8*)(Bs + swz((wn<<6)+(ni<<4)+cbase, l>>4));
    #pragma unroll
    for (int mi=0; mi<4; ++mi)
      #pragma unroll
      for (int ni=0; ni<4; ++ni)
        acc[mi][ni] = __builtin_amdgcn_mfma_f32_16x16x32_bf16(a[mi], b[ni], acc[mi][ni], 0,0,0);
  }
  // Epilogue: restage 128x128 tile through LDS in two 64-row halves, then
  // coalesced 16B stores. Column n'local = wn*64+ni*16+cbase directly equals
  // the destination inner index (h*32+c).
  for (int half=0; half<2; ++half){
    __syncthreads();
    if (wm == half){
      #pragma unroll
      for (int mi=0; mi<4; ++mi)
        #pragma unroll
        for (int ni=0; ni<4; ++ni){
          int coln = (wn<<6) + (ni<<4) + cbase;
          if (tt2 == 3){
            float bg = b_gate[((coln&31)<<2) + (coln>>5)];
            #pragma unroll
            for (int r=0; r<4; ++r){
              int row = (mi<<4) + rbase + r;
              float v = acc[mi][ni][r] + bg;
              Ep[row*132 + coln] = f2bf(1.f/(1.f + __expf(-v)));
            }
          } else {
            #pragma unroll
            for (int r=0; r<4; ++r){
              int row = (mi<<4) + rbase + r;
              Ep[row*132 + coln] = f2bf(acc[mi][ni][r]);
            }
          }
        }
    }
    __syncthreads();
    int row = (w<<4) + (l>>2);     // 0..63
    int a4  = l&3;
    union V16 { u16x4 q[2]; bf16x8 o; };
    if (tt2 < 3){
      // dst = tt*TEN + i*32768 + h*8192 + j*32 + c ; wave writes 1024B contiguous per h
      size_t base = (size_t)tt2*TEN_ELEMS + ((size_t)(m0>>8))*32768
                  + (size_t)((m0&255) + (half<<6) + row)*32;
      #pragma unroll
      for (int u=0; u<4; ++u){
        V16 v;
        v.q[0] = *(const u16x4*)(Ep + row*132 + (u<<5) + (a4<<3));
        v.q[1] = *(const u16x4*)(Ep + row*132 + (u<<5) + (a4<<3) + 4);
        *(bf16x8*)(qkv + base + (size_t)u*8192 + (a4<<3)) = v.o;
      }
    } else {
      size_t base = (size_t)(m0 + (half<<6) + row)*128;
      #pragma unroll
      for (int u=0; u<4; ++u){
        V16 v;
        v.q[0] = *(const u16x4*)(Ep + row*132 + (u<<5) + (a4<<3));
        v.q[1] = *(const u16x4*)(Ep + row*132 + (u<<5) + (a4<<3) + 4);
        *(bf16x8*)(gateb + base + (u<<5) + (a4<<3)) = v.o;
      }
    }
  }
}

// ---------------- K3: attention ----------------
__global__ __launch_bounds__(256,2) void k_attn(const u16* __restrict__ Qb,
                                                const u16* __restrict__ Kb,
                                                const u16* __restrict__ Vb,
                                                const float* __restrict__ bias_s,
                                                const u16* __restrict__ gateb,
                                                u16* __restrict__ Og){
  __shared__ __align__(16) u16 Ks[8192];
  __shared__ __align__(16) u16 Vs[8192];
  __shared__ __align__(16) u16 Pls[4][2176];   // per-wave [16][136]
  int t = threadIdx.x, l = t&63, w = t>>6;
  int i = blockIdx.x>>2, h = blockIdx.x&3;
  size_t base2 = ((size_t)(i*4+h))<<13;        // *8192 elements
  #pragma unroll
  for (int s=0; s<4; ++s){
    int idx = (s<<8) + t;
    gl16(Kb + base2 + ((size_t)idx<<3), Ks + (((s<<2)+w)<<9));
    gl16(Vb + base2 + ((size_t)idx<<3), Vs + (((s<<2)+w)<<9));
  }
  asm volatile("s_waitcnt vmcnt(0)" ::: "memory");
  __syncthreads();
  int cbase = l&15, rbase = (l>>4)<<2;
  bf16x8 kf[16];
  #pragma unroll
  for (int f=0; f<16; ++f)
    kf[f] = *(const bf16x8*)(Ks + ((f<<4)+cbase)*32 + ((l>>4)<<3));
  bf16x8 vf[8][2];
  #pragma unroll
  for (int ks=0; ks<8; ++ks)
    #pragma unroll
    for (int cf=0; cf<2; ++cf){
      bf16x8 v;
      #pragma unroll
      for (int e=0; e<8; ++e)
        v[e] = __builtin_bit_cast(__bf16, Vs[((ks<<5) + ((l>>4)<<3) + e)*32 + (cf<<4) + cbase]);
      vf[ks][cf] = v;
    }
  u16* myP = &Pls[w][0];
  const float SCALE = 0.17677669529663687f;   // 1/sqrt(32)
  #pragma unroll 1
  for (int sj=0; sj<4; ++sj){
    int jloc = (w<<6) + (sj<<4);
    bf16x8 qf = *(const bf16x8*)(Qb + base2 + (size_t)(jloc + cbase)*32 + ((l>>4)<<3));
    fx4 sacc[16];
    #pragma unroll
    for (int f=0; f<16; ++f) sacc[f] = (fx4){0.f,0.f,0.f,0.f};
    #pragma unroll
    for (int f=0; f<16; ++f)
      sacc[f] = __builtin_amdgcn_mfma_f32_16x16x32_bf16(qf, kf[f], sacc[f], 0,0,0);
    const float* bp = bias_s + ((size_t)((h<<8) + jloc + rbase)<<8) + cbase;
    #pragma unroll
    for (int f=0; f<16; ++f)
      #pragma unroll
      for (int r=0; r<4; ++r)
        sacc[f][r] = sacc[f][r]*SCALE + bp[(r<<8) + (f<<4)];
    float mx[4], inv[4];
    #pragma unroll
    for (int r=0; r<4; ++r){
      float m = sacc[0][r];
      #pragma unroll
      for (int f=1; f<16; ++f) m = fmaxf(m, sacc[f][r]);
      m = fmaxf(m, __shfl_xor(m,1));
      m = fmaxf(m, __shfl_xor(m,2));
      m = fmaxf(m, __shfl_xor(m,4));
      m = fmaxf(m, __shfl_xor(m,8));
      mx[r] = m;
    }
    #pragma unroll
    for (int r=0; r<4; ++r){
      float sum = 0.f;
      #pragma unroll
      for (int f=0; f<16; ++f){ float p = __expf(sacc[f][r]-mx[r]); sacc[f][r] = p; sum += p; }
      sum += __shfl_xor(sum,1); sum += __shfl_xor(sum,2);
      sum += __shfl_xor(sum,4); sum += __shfl_xor(sum,8);
      inv[r] = 1.f/sum;
    }
    fx4 oacc[2] = {};
    #pragma unroll
    for (int half=0; half<2; ++half){
      #pragma unroll
      for (int f=0; f<8; ++f){
        int fk = (half<<3)+f;
        #pragma unroll
        for (int r=0; r<4; ++r)
          myP[(rbase+r)*136 + (f<<4) + cbase] = f2bf(sacc[fk][r]*inv[r]);
      }
      asm volatile("s_waitcnt lgkmcnt(0)" ::: "memory");
      #pragma unroll
      for (int k2=0; k2<4; ++k2){
        const bf16x8 pa = *(const bf16x8*)(myP + cbase*136 + (k2<<5) + ((l>>4)<<3));
        int ks = (half<<2)+k2;
        oacc[0] = __builtin_amdgcn_mfma_f32_16x16x32_bf16(pa, vf[ks][0], oacc[0], 0,0,0);
        oacc[1] = __builtin_amdgcn_mfma_f32_16x16x32_bf16(pa, vf[ks][1], oacc[1], 0,0,0);
      }
    }
    #pragma unroll
    for (int cf=0; cf<2; ++cf)
      #pragma unroll
      for (int r=0; r<4; ++r){
        int j = jloc + rbase + r;
        size_t pix = (((size_t)i)<<8) + j;
        int ch = (h<<5) + (cf<<4) + cbase;     // permuted layout [pix][h*32+c]
        float gg = bf2f(gateb[(pix<<7) + ch]);
        Og[(pix<<7) + ch] = f2bf(oacc[cf][r]*gg);
      }
  }
}

// ---------------- K4: output GEMM ----------------
__global__ __launch_bounds__(256,3) void k_out(const u16* __restrict__ og,
                                               const u16* __restrict__ wT,
                                               const float* __restrict__ bo,
                                               float* __restrict__ out){
  __shared__ __align__(16) u16 As[4096];
  __shared__ __align__(16) u16 Bs[4096];
  int t = threadIdx.x, l = t&63, w = t>>6;
  int m0 = blockIdx.x<<7;
  int wm = w>>1, wn = w&1;
  int rbase = (l>>4)<<2, cbase = l&15;
  fx4 acc[4][4] = {};
  for (int ks=0; ks<4; ++ks){
    int k0 = ks<<5;
    __syncthreads();
    #pragma unroll
    for (int s=0; s<2; ++s){
      int idx = (s<<8)+t, row = idx>>2, ccL = idx&3;
      int ccG = (ccL - (row>>1))&3;
      gl16(og + (size_t)(m0+row)*128 + k0 + (ccG<<3), As + (((s<<2)+w)<<9));
      gl16(wT + (size_t)row*128 + k0 + (ccG<<3), Bs + (((s<<2)+w)<<9));
    }
    asm volatile("s_waitcnt vmcnt(0)" ::: "memory");
    __syncthreads();
    bf16x8 a[4], b[4];
    #pragma unroll
    for (int mi=0; mi<4; ++mi)
      a[mi] = *(const bf16x8*)(As + swz((wm<<6)+(mi<<4)+cbase, l>>4));
    #pragma unroll
    for (int ni=0; ni<4; ++ni)
      b[ni] = *(const bf16x8*)(Bs + swz((wn<<6)+(ni<<4)+cbase, l>>4));
    #pragma unroll
    for (int mi=0; mi<4; ++mi)
      #pragma unroll
      for (int ni=0; ni<4; ++ni)
        acc[mi][ni] = __builtin_amdgcn_mfma_f32_16x16x32_bf16(a[mi], b[ni], acc[mi][ni], 0,0,0);
  }
  #pragma unroll
  for (int mi=0; mi<4; ++mi)
    #pragma unroll
    for (int ni=0; ni<4; ++ni){
      int n = (wn<<6)+(ni<<4)+cbase;
      float bn = bo[n];
      #pragma unroll
      for (int r=0; r<4; ++r){
        int m = m0 + (wm<<6)+(mi<<4)+rbase+r;
        out[(((size_t)m)<<7)+n] = acc[mi][ni][r] + bn;
      }
    }
}

extern "C" void kernel_launch(void* const* d_in, const int* in_sizes, int n_in,
                              void* d_out, int out_size, void* d_ws, size_t ws_size,
                              hipStream_t stream) {
  (void)in_sizes; (void)n_in; (void)out_size; (void)ws_size;
  const float* x2d    = (const float*)d_in[0];
  const float* ln_g   = (const float*)d_in[1];
  const float* ln_b   = (const float*)d_in[2];
  const float* W_qkv  = (const float*)d_in[3];
  const float* W_bias = (const float*)d_in[4];
  const float* W_gate = (const float*)d_in[5];
  const float* b_gate = (const float*)d_in[6];
  const float* W_out  = (const float*)d_in[7];
  const float* b_out  = (const float*)d_in[8];
  float* out = (float*)d_out;
  char* ws = (char*)d_ws;
  u16*   lnx    = (u16*)(ws);
  u16*   wcat   = (u16*)(ws + OFF_WCAT);
  u16*   woutT  = (u16*)(ws + OFF_WOUT);
  u16*   qkvb   = (u16*)(ws + OFF_Q);
  float* bias_s = (float*)(ws + OFF_BIAS);
  u16*   gateb  = (u16*)(ws + OFF_GATE);
  u16*   og     = lnx;   // reuse: lnx dead after k_qkv

  hipLaunchKernelGGL(k_prep, dim3(256),      dim3(256), 0, stream, W_qkv, W_gate, W_out, wcat, woutT);
  hipLaunchKernelGGL(k_ln,   dim3(2048),     dim3(256), 0, stream, x2d, ln_g, ln_b, W_bias, lnx, bias_s);
  hipLaunchKernelGGL(k_qkv,  dim3(512,4),    dim3(256), 0, stream, lnx, wcat, b_gate, qkvb, gateb);
  hipLaunchKernelGGL(k_attn, dim3(1024),     dim3(256), 0, stream, qkvb, qkvb+TEN_ELEMS, qkvb+2*TEN_ELEMS, bias_s, gateb, og);
  hipLaunchKernelGGL(k_out,  dim3(512),      dim3(256), 0, stream, og, woutT, b_out, out);
}